// Round 8
// baseline (269.731 us; speedup 1.0000x reference)
//
#include <hip/hip_runtime.h>
#include <hip/hip_bf16.h>

// LGM loss: logits/margin_logits [8192,10000] f32 + scalar likelihood.
// R8: DRAM-page-locality attack. Ledger: store instr shape null (R2/R3),
// NT null (R6), store/compute interleave negative (R7), occupancy +27,
// pipeline +10. Untested axis: MACRO write pattern. Old mapping scattered
// 512B chunks over 65K distinct 40KB-apart rows chip-wide (page thrash,
// ~3.4 TB/s). New: persistent 512 blocks; each owns (mt band, 10 consecutive
// nt) -> every output row is written SEQUENTIALLY (8 monotone streams/row),
// concurrent row-targets 65K -> 16K. Epilogue back to R6 style (R7's
// interleaved EMIT regressed). Everything else identical to R6.

#define ALPHA_ 0.1f
constexpr int BATCH = 8192;
constexpr int NCLS  = 10000;
constexpr int FDIM  = 256;

typedef __attribute__((ext_vector_type(8))) short bf16x8;
typedef __attribute__((ext_vector_type(4))) float f32x4;

__device__ __forceinline__ unsigned short f2bf(float f) {
  unsigned int u = __float_as_uint(f);
  u += 0x7FFF + ((u >> 16) & 1);   // round-to-nearest-even
  return (unsigned short)(u >> 16);
}

// One wave per row: convert f32 row -> bf16 into ws, and compute sum(x*x).
__global__ void prep_kernel(const float* __restrict__ feat,
                            const float* __restrict__ centers,
                            unsigned short* __restrict__ fbf,
                            unsigned short* __restrict__ cbf,
                            float* __restrict__ fsq,
                            float* __restrict__ csq) {
  int gw = (int)((blockIdx.x * blockDim.x + threadIdx.x) >> 6);
  int lane = threadIdx.x & 63;
  if (gw >= BATCH + NCLS) return;
  const float* src; unsigned short* dst; float* sq;
  if (gw < BATCH) {
    src = feat + (size_t)gw * FDIM; dst = fbf + (size_t)gw * FDIM; sq = fsq + gw;
  } else {
    int r = gw - BATCH;
    src = centers + (size_t)r * FDIM; dst = cbf + (size_t)r * FDIM; sq = csq + r;
  }
  float4 v = reinterpret_cast<const float4*>(src)[lane];   // 64 lanes x 16B = 256 f32
  ushort4 b;
  b.x = f2bf(v.x); b.y = f2bf(v.y); b.z = f2bf(v.z); b.w = f2bf(v.w);
  reinterpret_cast<ushort4*>(dst)[lane] = b;
  float s = v.x*v.x + v.y*v.y + v.z*v.z + v.w*v.w;
  #pragma unroll
  for (int off = 32; off >= 1; off >>= 1) s += __shfl_xor(s, off, 64);
  if (lane == 0) *sq = s;
}

// 128x128 tile, BK=64, 8 waves (2Mx4N), each wave 64x32 via 4x2 frags of 16x16x32.
#define BM 128
#define BN 128
#define BK 64
#define GRID 512
constexpr int NTN = 79;                 // N tiles per 128-row band

__global__ __launch_bounds__(512, 4)
void gemm_kernel(const unsigned short* __restrict__ fbf,
                 const unsigned short* __restrict__ cbf,
                 const float* __restrict__ fsq,
                 const float* __restrict__ csq,
                 const int* __restrict__ label,
                 float* __restrict__ out_logits,
                 float* __restrict__ out_margin,
                 float* __restrict__ lik_row) {
  // Double-buffered, XOR-swizzled (slot = chunk ^ (row&7), 16B chunks).
  __shared__ unsigned short As[2][BM * BK];   // 16 KB each
  __shared__ unsigned short Bs[2][BN * BK];   // 16 KB each

  const int bid  = blockIdx.x;          // 0..511
  // Band-affine mapping: XCD g=bid&7 owns mt bands [8g, 8g+8); within a band,
  // 8 sub-blocks sweep consecutive nt ranges of ~10 tiles each.
  const int g    = bid & 7;
  const int s    = bid >> 3;            // 0..63
  const int mt   = g * 8 + (s >> 3);    // 0..63
  const int sub  = s & 7;               // 0..7
  const int nt0  = sub * 10;
  const int nt1  = (nt0 + 10 < NTN) ? (nt0 + 10) : NTN;

  const int tid  = threadIdx.x;
  const int lane = tid & 63;
  const int wid  = tid >> 6;            // 0..7
  const int wr   = (wid >> 2) * 64;     // 2 waves in M
  const int wc   = (wid & 3) * 32;      // 4 waves in N
  const int sr   = tid >> 3;            // staging row 0..63
  const int sc   = tid & 7;             // staging 16B chunk 0..7
  const int mloc  = wr + (lane & 15);
  const int nbase = wc + ((lane >> 4) << 2);

  const size_t a_base = (size_t)(mt * BM) * FDIM;

  f32x4 acc[4][2];
  bf16x8 va[2], vb[2];

  #define LOADT(c0_, k0_) do {                                                 \
    _Pragma("unroll")                                                          \
    for (int j = 0; j < 2; ++j) {                                              \
      int r = j * 64 + sr;                                                     \
      va[j] = *reinterpret_cast<const bf16x8*>(fbf + a_base + (size_t)r * FDIM + (k0_) + sc * 8); \
      int cc = (c0_) + r; cc = (cc < NCLS) ? cc : (NCLS - 1);                  \
      vb[j] = *reinterpret_cast<const bf16x8*>(cbf + (size_t)cc * FDIM + (k0_) + sc * 8); \
    }                                                                          \
  } while (0)

  #define STORET(b_) do {                                                      \
    _Pragma("unroll")                                                          \
    for (int j = 0; j < 2; ++j) {                                              \
      int r = j * 64 + sr;                                                     \
      int off = r * BK + ((sc ^ (r & 7)) * 8);                                 \
      *reinterpret_cast<bf16x8*>(&As[b_][off]) = va[j];                        \
      *reinterpret_cast<bf16x8*>(&Bs[b_][off]) = vb[j];                        \
    }                                                                          \
  } while (0)

  for (int nt = nt0; nt < nt1; ++nt) {
    const int c0 = nt * BN;

    #pragma unroll
    for (int i = 0; i < 4; i++)
      #pragma unroll
      for (int j = 0; j < 2; j++) acc[i][j] = (f32x4){0.f, 0.f, 0.f, 0.f};

    LOADT(c0, 0);
    STORET(0);

    #pragma unroll
    for (int kc = 0; kc < FDIM / BK; ++kc) {
      const int cur = kc & 1;
      if (kc < FDIM / BK - 1) LOADT(c0, (kc + 1) * BK);
      __syncthreads();                          // buf[cur] writes visible
      #pragma unroll
      for (int kk = 0; kk < BK / 32; ++kk) {
        const int ch = kk * 4 + (lane >> 4);    // 16B chunk within row
        bf16x8 a[4], b[2];
        #pragma unroll
        for (int i = 0; i < 4; i++) {
          int row = wr + i * 16 + (lane & 15);
          a[i] = *reinterpret_cast<const bf16x8*>(&As[cur][row * BK + ((ch ^ (row & 7)) * 8)]);
        }
        #pragma unroll
        for (int j = 0; j < 2; j++) {
          int row = wc + j * 16 + (lane & 15);
          b[j] = *reinterpret_cast<const bf16x8*>(&Bs[cur][row * BK + ((ch ^ (row & 7)) * 8)]);
        }
        // Swapped operands: per lane, reg r = 4 consecutive N columns at one M row.
        #pragma unroll
        for (int i = 0; i < 4; i++)
          #pragma unroll
          for (int j = 0; j < 2; j++)
            acc[i][j] = __builtin_amdgcn_mfma_f32_16x16x32_bf16(b[j], a[i], acc[i][j], 0, 0, 0);
      }
      if (kc < FDIM / BK - 1) STORET(cur ^ 1);  // fill other buffer
      else __syncthreads();                     // protect As/Bs before next nt's STORET
    }

    // Epilogue (R6 style): logits = acc - 0.5*(fsq+csq); margin; lik fold.
    #pragma unroll
    for (int i = 0; i < 4; i++) {
      int m = mt * BM + mloc + i * 16;
      float fs = fsq[m];
      int lb = label[m];
      size_t rowoff = (size_t)m * NCLS;
      #pragma unroll
      for (int j = 0; j < 2; j++) {
        int n0 = c0 + nbase + j * 16;
        if (n0 >= NCLS) continue;   // NCLS%4==0 and n0%4==0 -> float4 all-or-nothing
        float4 cs = *reinterpret_cast<const float4*>(&csq[n0]);
        f32x4 v = acc[i][j];
        f32x4 lg;
        lg[0] = v[0] - 0.5f * (fs + cs.x);
        lg[1] = v[1] - 0.5f * (fs + cs.y);
        lg[2] = v[2] - 0.5f * (fs + cs.z);
        lg[3] = v[3] - 0.5f * (fs + cs.w);
        *reinterpret_cast<f32x4*>(&out_logits[rowoff + n0]) = lg;
        f32x4 mg;
        mg[0] = (lb == n0    ) ? lg[0] * (1.0f + ALPHA_) : lg[0];
        mg[1] = (lb == n0 + 1) ? lg[1] * (1.0f + ALPHA_) : lg[1];
        mg[2] = (lb == n0 + 2) ? lg[2] * (1.0f + ALPHA_) : lg[2];
        mg[3] = (lb == n0 + 3) ? lg[3] * (1.0f + ALPHA_) : lg[3];
        *reinterpret_cast<f32x4*>(&out_margin[rowoff + n0]) = mg;
        if (lb >= n0 && lb < n0 + 4) {
          float lv = (lb == n0) ? lg[0] : (lb == n0 + 1) ? lg[1]
                   : (lb == n0 + 2) ? lg[2] : lg[3];
          lik_row[m] = -lv;   // exactly one thread in grid writes each m
        }
      }
    }
  }
  #undef LOADT
  #undef STORET
}

// likelihood = (1/B) * sum_m lik_row[m]; 1024 threads, deterministic tree.
__global__ void lik_reduce_kernel(const float* __restrict__ lik_row,
                                  float* __restrict__ out) {
  int t = threadIdx.x;  // 1024
  float v = 0.f;
  #pragma unroll
  for (int i = 0; i < BATCH / 1024; i++) v += lik_row[t + i * 1024];
  #pragma unroll
  for (int off = 32; off >= 1; off >>= 1) v += __shfl_xor(v, off, 64);
  __shared__ float red[16];
  if ((t & 63) == 0) red[t >> 6] = v;
  __syncthreads();
  if (t == 0) {
    float s = 0.f;
    #pragma unroll
    for (int i = 0; i < 16; i++) s += red[i];
    out[0] = s * (1.0f / BATCH);
  }
}

extern "C" void kernel_launch(void* const* d_in, const int* in_sizes, int n_in,
                              void* d_out, int out_size, void* d_ws, size_t ws_size,
                              hipStream_t stream) {
  const float* feat    = (const float*)d_in[0];
  const int*   label   = (const int*)d_in[1];
  const float* centers = (const float*)d_in[2];

  float* out        = (float*)d_out;
  float* out_logits = out;
  float* out_margin = out + (size_t)BATCH * NCLS;
  float* out_lik    = out + 2 * (size_t)BATCH * NCLS;

  char* ws = (char*)d_ws;
  unsigned short* fbf = (unsigned short*)ws;                                   // 4 MB
  unsigned short* cbf = (unsigned short*)(ws + (size_t)BATCH * FDIM * 2);      // 5 MB
  float* fsq     = (float*)(ws + (size_t)BATCH * FDIM * 2 + (size_t)NCLS * FDIM * 2);
  float* csq     = fsq + BATCH;
  float* lik_row = csq + NCLS;

  prep_kernel<<<(BATCH + NCLS) / 4, 256, 0, stream>>>(feat, centers, fbf, cbf, fsq, csq);
  gemm_kernel<<<GRID, 512, 0, stream>>>(
      fbf, cbf, fsq, csq, label, out_logits, out_margin, lik_row);
  lik_reduce_kernel<<<1, 1024, 0, stream>>>(lik_row, out_lik);
}

// Round 9
// 228.949 us; speedup vs baseline: 1.1781x; 1.1781x over previous
//
#include <hip/hip_runtime.h>
#include <hip/hip_bf16.h>

// LGM loss: logits/margin_logits [8192,10000] f32 + scalar likelihood.
// R9: 256x256 tiles to HALVE read traffic. Model that finally matches data:
// memory-side fabric moves writes(655MB) + panel re-reads(NWG*(BM+BN)*512B)
// at ~6.7 TB/s (fill-kernel calib). R6 = 1.30GB -> 194us = observed GEMM.
// Store-side tweaks were all null because traffic, not transactions, is the
// cost. 256^2 tile: reads 647->328MB. BK=32 keeps LDS at 64KB static
// (1 block/CU, 16 waves, 4/SIMD — same waves/SIMD as R6). R8's private-range
// mapping reverted: co-resident blocks sweep consecutive nt of one band
// (page-coherent writes, proven by R8's -70us when broken).

#define ALPHA_ 0.1f
constexpr int BATCH = 8192;
constexpr int NCLS  = 10000;
constexpr int FDIM  = 256;

typedef __attribute__((ext_vector_type(8))) short bf16x8;
typedef __attribute__((ext_vector_type(4))) float f32x4;

__device__ __forceinline__ unsigned short f2bf(float f) {
  unsigned int u = __float_as_uint(f);
  u += 0x7FFF + ((u >> 16) & 1);   // round-to-nearest-even
  return (unsigned short)(u >> 16);
}

// One wave per row: convert f32 row -> bf16 into ws, and compute sum(x*x).
__global__ void prep_kernel(const float* __restrict__ feat,
                            const float* __restrict__ centers,
                            unsigned short* __restrict__ fbf,
                            unsigned short* __restrict__ cbf,
                            float* __restrict__ fsq,
                            float* __restrict__ csq) {
  int gw = (int)((blockIdx.x * blockDim.x + threadIdx.x) >> 6);
  int lane = threadIdx.x & 63;
  if (gw >= BATCH + NCLS) return;
  const float* src; unsigned short* dst; float* sq;
  if (gw < BATCH) {
    src = feat + (size_t)gw * FDIM; dst = fbf + (size_t)gw * FDIM; sq = fsq + gw;
  } else {
    int r = gw - BATCH;
    src = centers + (size_t)r * FDIM; dst = cbf + (size_t)r * FDIM; sq = csq + r;
  }
  float4 v = reinterpret_cast<const float4*>(src)[lane];   // 64 lanes x 16B = 256 f32
  ushort4 b;
  b.x = f2bf(v.x); b.y = f2bf(v.y); b.z = f2bf(v.z); b.w = f2bf(v.w);
  reinterpret_cast<ushort4*>(dst)[lane] = b;
  float s = v.x*v.x + v.y*v.y + v.z*v.z + v.w*v.w;
  #pragma unroll
  for (int off = 32; off >= 1; off >>= 1) s += __shfl_xor(s, off, 64);
  if (lane == 0) *sq = s;
}

// 256x256 tile, BK=32, 16 waves (4Mx4N), each wave 64x64 via 4x4 frags.
#define BM 256
#define BN 256
#define BK 32
constexpr int NTN = 40;                  // ceil(10000/256)
constexpr int NWG = (BATCH / BM) * NTN;  // 32*40 = 1280 = 5*256, 1280%8==0

__global__ __launch_bounds__(1024, 4)
void gemm_kernel(const unsigned short* __restrict__ fbf,
                 const unsigned short* __restrict__ cbf,
                 const float* __restrict__ fsq,
                 const float* __restrict__ csq,
                 const int* __restrict__ label,
                 float* __restrict__ out_logits,
                 float* __restrict__ out_margin,
                 float* __restrict__ lik_row) {
  // Double-buffered, XOR-swizzled (slot = chunk ^ (row&3), 16B chunks, 4/row).
  __shared__ unsigned short As[2][BM * BK];   // 16 KB each
  __shared__ unsigned short Bs[2][BN * BK];   // 16 KB each  -> 64 KB total

  // XCD-bijective split, nt-fastest: XCD g's co-resident 32 blocks cover 32
  // consecutive nt of one mt band -> shared A panel + page-coherent writes.
  int bid = blockIdx.x;
  int wg = (bid & 7) * (NWG >> 3) + (bid >> 3);
  int mt = wg / NTN;
  int nt = wg - mt * NTN;

  const int tid  = threadIdx.x;
  const int lane = tid & 63;
  const int wid  = tid >> 6;            // 0..15
  const int wr   = (wid >> 2) * 64;     // 4 waves in M
  const int wc   = (wid & 3) * 64;      // 4 waves in N
  const int sr   = tid >> 2;            // staging row 0..255
  const int sc   = tid & 3;             // staging 16B chunk 0..3
  const int mloc  = wr + (lane & 15);
  const int nbase = wc + ((lane >> 4) << 2);
  const int ch    = lane >> 4;          // frag k-chunk 0..3

  f32x4 acc[4][4];
  #pragma unroll
  for (int i = 0; i < 4; i++)
    #pragma unroll
    for (int j = 0; j < 4; j++) acc[i][j] = (f32x4){0.f, 0.f, 0.f, 0.f};

  const size_t a_base = (size_t)(mt * BM) * FDIM;
  const int c0 = nt * BN;

  bf16x8 va, vb;
  #define LOADT(k0_) do {                                                      \
    va = *reinterpret_cast<const bf16x8*>(fbf + a_base + (size_t)sr * FDIM + (k0_) + sc * 8); \
    int cc = c0 + sr; cc = (cc < NCLS) ? cc : (NCLS - 1);                      \
    vb = *reinterpret_cast<const bf16x8*>(cbf + (size_t)cc * FDIM + (k0_) + sc * 8); \
  } while (0)

  #define STORET(b_) do {                                                      \
    int off = sr * BK + ((sc ^ (sr & 3)) * 8);                                 \
    *reinterpret_cast<bf16x8*>(&As[b_][off]) = va;                             \
    *reinterpret_cast<bf16x8*>(&Bs[b_][off]) = vb;                             \
  } while (0)

  LOADT(0);
  STORET(0);

  #pragma unroll
  for (int kc = 0; kc < FDIM / BK; ++kc) {
    const int cur = kc & 1;
    if (kc < FDIM / BK - 1) LOADT((kc + 1) * BK);
    __syncthreads();                          // buf[cur] writes visible
    bf16x8 a[4], b[4];
    #pragma unroll
    for (int i = 0; i < 4; i++) {
      int row = wr + i * 16 + (lane & 15);
      a[i] = *reinterpret_cast<const bf16x8*>(&As[cur][row * BK + ((ch ^ (row & 3)) * 8)]);
    }
    #pragma unroll
    for (int j = 0; j < 4; j++) {
      int row = wc + j * 16 + (lane & 15);
      b[j] = *reinterpret_cast<const bf16x8*>(&Bs[cur][row * BK + ((ch ^ (row & 3)) * 8)]);
    }
    // Swapped operands: per lane, reg r = 4 consecutive N columns at one M row.
    #pragma unroll
    for (int i = 0; i < 4; i++)
      #pragma unroll
      for (int j = 0; j < 4; j++)
        acc[i][j] = __builtin_amdgcn_mfma_f32_16x16x32_bf16(b[j], a[i], acc[i][j], 0, 0, 0);
    if (kc < FDIM / BK - 1) STORET(cur ^ 1);  // fill other buffer
  }

  // Epilogue: logits = acc - 0.5*(fsq+csq); margin; lik fold.
  #pragma unroll
  for (int i = 0; i < 4; i++) {
    int m = mt * BM + mloc + i * 16;
    float fs = fsq[m];
    int lb = label[m];
    size_t rowoff = (size_t)m * NCLS;
    #pragma unroll
    for (int j = 0; j < 4; j++) {
      int n0 = c0 + nbase + j * 16;
      if (n0 >= NCLS) continue;   // NCLS%4==0 and n0%4==0 -> float4 all-or-nothing
      float4 cs = *reinterpret_cast<const float4*>(&csq[n0]);
      f32x4 v = acc[i][j];
      f32x4 lg;
      lg[0] = v[0] - 0.5f * (fs + cs.x);
      lg[1] = v[1] - 0.5f * (fs + cs.y);
      lg[2] = v[2] - 0.5f * (fs + cs.z);
      lg[3] = v[3] - 0.5f * (fs + cs.w);
      *reinterpret_cast<f32x4*>(&out_logits[rowoff + n0]) = lg;
      f32x4 mg;
      mg[0] = (lb == n0    ) ? lg[0] * (1.0f + ALPHA_) : lg[0];
      mg[1] = (lb == n0 + 1) ? lg[1] * (1.0f + ALPHA_) : lg[1];
      mg[2] = (lb == n0 + 2) ? lg[2] * (1.0f + ALPHA_) : lg[2];
      mg[3] = (lb == n0 + 3) ? lg[3] * (1.0f + ALPHA_) : lg[3];
      *reinterpret_cast<f32x4*>(&out_margin[rowoff + n0]) = mg;
      if (lb >= n0 && lb < n0 + 4) {
        float lv = (lb == n0) ? lg[0] : (lb == n0 + 1) ? lg[1]
                 : (lb == n0 + 2) ? lg[2] : lg[3];
        lik_row[m] = -lv;   // exactly one thread in grid writes each m
      }
    }
  }
  #undef LOADT
  #undef STORET
}

// likelihood = (1/B) * sum_m lik_row[m]; 1024 threads, deterministic tree.
__global__ void lik_reduce_kernel(const float* __restrict__ lik_row,
                                  float* __restrict__ out) {
  int t = threadIdx.x;  // 1024
  float v = 0.f;
  #pragma unroll
  for (int i = 0; i < BATCH / 1024; i++) v += lik_row[t + i * 1024];
  #pragma unroll
  for (int off = 32; off >= 1; off >>= 1) v += __shfl_xor(v, off, 64);
  __shared__ float red[16];
  if ((t & 63) == 0) red[t >> 6] = v;
  __syncthreads();
  if (t == 0) {
    float s = 0.f;
    #pragma unroll
    for (int i = 0; i < 16; i++) s += red[i];
    out[0] = s * (1.0f / BATCH);
  }
}

extern "C" void kernel_launch(void* const* d_in, const int* in_sizes, int n_in,
                              void* d_out, int out_size, void* d_ws, size_t ws_size,
                              hipStream_t stream) {
  const float* feat    = (const float*)d_in[0];
  const int*   label   = (const int*)d_in[1];
  const float* centers = (const float*)d_in[2];

  float* out        = (float*)d_out;
  float* out_logits = out;
  float* out_margin = out + (size_t)BATCH * NCLS;
  float* out_lik    = out + 2 * (size_t)BATCH * NCLS;

  char* ws = (char*)d_ws;
  unsigned short* fbf = (unsigned short*)ws;                                   // 4 MB
  unsigned short* cbf = (unsigned short*)(ws + (size_t)BATCH * FDIM * 2);      // 5 MB
  float* fsq     = (float*)(ws + (size_t)BATCH * FDIM * 2 + (size_t)NCLS * FDIM * 2);
  float* csq     = fsq + BATCH;
  float* lik_row = csq + NCLS;

  prep_kernel<<<(BATCH + NCLS) / 4, 256, 0, stream>>>(feat, centers, fbf, cbf, fsq, csq);
  gemm_kernel<<<NWG, 1024, 0, stream>>>(
      fbf, cbf, fsq, csq, label, out_logits, out_margin, lik_row);
  lik_reduce_kernel<<<1, 1024, 0, stream>>>(lik_row, out_lik);
}

// Round 10
// 209.321 us; speedup vs baseline: 1.2886x; 1.0938x over previous
//
#include <hip/hip_runtime.h>
#include <hip/hip_bf16.h>

// LGM loss: logits/margin_logits [8192,10000] f32 + scalar likelihood.
// R10: back to R6 skeleton (best, 200us). R9 falsified the read-traffic
// model (reads are L2-hits, not HBM). Per-CU serial budget for R6:
// writes 95 + LDS 50 + MFMA 10 + overhead 25 ~= 180 = observed. Attack LDS:
// 64x64 wave tiles cost 16 B ds_read per output (vs 24 at 64x32) -> 4 waves
// of 64x64 per 128x128 tile, 256 thr. BK=32 halves LDS to 32KB -> 4
// blocks/CU (4 independent barrier domains/CU vs R6's 2 = better phase
// desync at identical 16 waves/CU).

#define ALPHA_ 0.1f
constexpr int BATCH = 8192;
constexpr int NCLS  = 10000;
constexpr int FDIM  = 256;

typedef __attribute__((ext_vector_type(8))) short bf16x8;
typedef __attribute__((ext_vector_type(4))) float f32x4;

__device__ __forceinline__ unsigned short f2bf(float f) {
  unsigned int u = __float_as_uint(f);
  u += 0x7FFF + ((u >> 16) & 1);   // round-to-nearest-even
  return (unsigned short)(u >> 16);
}

// One wave per row: convert f32 row -> bf16 into ws, and compute sum(x*x).
__global__ void prep_kernel(const float* __restrict__ feat,
                            const float* __restrict__ centers,
                            unsigned short* __restrict__ fbf,
                            unsigned short* __restrict__ cbf,
                            float* __restrict__ fsq,
                            float* __restrict__ csq) {
  int gw = (int)((blockIdx.x * blockDim.x + threadIdx.x) >> 6);
  int lane = threadIdx.x & 63;
  if (gw >= BATCH + NCLS) return;
  const float* src; unsigned short* dst; float* sq;
  if (gw < BATCH) {
    src = feat + (size_t)gw * FDIM; dst = fbf + (size_t)gw * FDIM; sq = fsq + gw;
  } else {
    int r = gw - BATCH;
    src = centers + (size_t)r * FDIM; dst = cbf + (size_t)r * FDIM; sq = csq + r;
  }
  float4 v = reinterpret_cast<const float4*>(src)[lane];   // 64 lanes x 16B = 256 f32
  ushort4 b;
  b.x = f2bf(v.x); b.y = f2bf(v.y); b.z = f2bf(v.z); b.w = f2bf(v.w);
  reinterpret_cast<ushort4*>(dst)[lane] = b;
  float s = v.x*v.x + v.y*v.y + v.z*v.z + v.w*v.w;
  #pragma unroll
  for (int off = 32; off >= 1; off >>= 1) s += __shfl_xor(s, off, 64);
  if (lane == 0) *sq = s;
}

// 128x128 tile, BK=32, 4 waves (2Mx2N), each wave 64x64 via 4x4 frags.
#define BM 128
#define BN 128
#define BK 32
constexpr int NTN = 79;                  // N tiles
constexpr int NWG = (BATCH / BM) * NTN;  // 5056 == 8 * 632

__global__ __launch_bounds__(256, 4)
void gemm_kernel(const unsigned short* __restrict__ fbf,
                 const unsigned short* __restrict__ cbf,
                 const float* __restrict__ fsq,
                 const float* __restrict__ csq,
                 const int* __restrict__ label,
                 float* __restrict__ out_logits,
                 float* __restrict__ out_margin,
                 float* __restrict__ lik_row) {
  // Double-buffered; swizzle slot = chunk ^ ((row>>1)&3): uniform 2-way banks
  // on both frag reads (16 rows -> each bank-quad exactly 2x) and staging.
  __shared__ unsigned short As[2][BM * BK];   // 8 KB each
  __shared__ unsigned short Bs[2][BN * BK];   // 8 KB each  -> 32 KB total

  // XCD-bijective split, nt-fastest within each XCD chunk (A-panel L2 reuse,
  // page-coherent band writes — R8 proved breaking this costs 70us).
  int bid = blockIdx.x;
  int wg = (bid & 7) * (NWG >> 3) + (bid >> 3);
  int mt = wg / NTN;
  int nt = wg - mt * NTN;

  const int tid  = threadIdx.x;
  const int lane = tid & 63;
  const int wid  = tid >> 6;            // 0..3
  const int wr   = (wid >> 1) * 64;     // 2 waves in M
  const int wc   = (wid & 1) * 64;      // 2 waves in N
  const int sr   = tid >> 1;            // staging row 0..127
  const int scp  = (tid & 1) * 2;       // staging chunk pair base (0 or 2)
  const int mloc  = wr + (lane & 15);
  const int nbase = wc + ((lane >> 4) << 2);
  const int ch    = lane >> 4;          // frag k-chunk 0..3

  f32x4 acc[4][4];
  #pragma unroll
  for (int i = 0; i < 4; i++)
    #pragma unroll
    for (int j = 0; j < 4; j++) acc[i][j] = (f32x4){0.f, 0.f, 0.f, 0.f};

  const size_t a_base = (size_t)(mt * BM) * FDIM;
  const int c0 = nt * BN;

  bf16x8 va0, va1, vb0, vb1;
  #define LOADT(k0_) do {                                                      \
    const unsigned short* ap = fbf + a_base + (size_t)sr * FDIM + (k0_) + scp * 8; \
    va0 = *reinterpret_cast<const bf16x8*>(ap);                                \
    va1 = *reinterpret_cast<const bf16x8*>(ap + 8);                            \
    int cc = c0 + sr; cc = (cc < NCLS) ? cc : (NCLS - 1);                      \
    const unsigned short* bp = cbf + (size_t)cc * FDIM + (k0_) + scp * 8;      \
    vb0 = *reinterpret_cast<const bf16x8*>(bp);                                \
    vb1 = *reinterpret_cast<const bf16x8*>(bp + 8);                            \
  } while (0)

  #define STORET(b_) do {                                                      \
    int f_ = (sr >> 1) & 3;                                                    \
    int o0 = sr * BK + ((scp ^ f_) * 8);                                       \
    int o1 = sr * BK + (((scp + 1) ^ f_) * 8);                                 \
    *reinterpret_cast<bf16x8*>(&As[b_][o0]) = va0;                             \
    *reinterpret_cast<bf16x8*>(&As[b_][o1]) = va1;                             \
    *reinterpret_cast<bf16x8*>(&Bs[b_][o0]) = vb0;                             \
    *reinterpret_cast<bf16x8*>(&Bs[b_][o1]) = vb1;                             \
  } while (0)

  LOADT(0);
  STORET(0);

  #pragma unroll
  for (int kc = 0; kc < FDIM / BK; ++kc) {
    const int cur = kc & 1;
    if (kc < FDIM / BK - 1) LOADT((kc + 1) * BK);
    __syncthreads();                          // buf[cur] writes visible
    bf16x8 a[4], b[4];
    #pragma unroll
    for (int i = 0; i < 4; i++) {
      int row = wr + i * 16 + (lane & 15);
      a[i] = *reinterpret_cast<const bf16x8*>(&As[cur][row * BK + ((ch ^ ((row >> 1) & 3)) * 8)]);
    }
    #pragma unroll
    for (int j = 0; j < 4; j++) {
      int row = wc + j * 16 + (lane & 15);
      b[j] = *reinterpret_cast<const bf16x8*>(&Bs[cur][row * BK + ((ch ^ ((row >> 1) & 3)) * 8)]);
    }
    // Swapped operands: per lane, reg r = 4 consecutive N columns at one M row.
    #pragma unroll
    for (int i = 0; i < 4; i++)
      #pragma unroll
      for (int j = 0; j < 4; j++)
        acc[i][j] = __builtin_amdgcn_mfma_f32_16x16x32_bf16(b[j], a[i], acc[i][j], 0, 0, 0);
    if (kc < FDIM / BK - 1) STORET(cur ^ 1);  // fill other buffer
  }

  // Epilogue: logits = acc - 0.5*(fsq+csq); margin; lik fold.
  #pragma unroll
  for (int i = 0; i < 4; i++) {
    int m = mt * BM + mloc + i * 16;
    float fs = fsq[m];
    int lb = label[m];
    size_t rowoff = (size_t)m * NCLS;
    #pragma unroll
    for (int j = 0; j < 4; j++) {
      int n0 = c0 + nbase + j * 16;
      if (n0 >= NCLS) continue;   // NCLS%4==0 and n0%4==0 -> float4 all-or-nothing
      float4 cs = *reinterpret_cast<const float4*>(&csq[n0]);
      f32x4 v = acc[i][j];
      f32x4 lg;
      lg[0] = v[0] - 0.5f * (fs + cs.x);
      lg[1] = v[1] - 0.5f * (fs + cs.y);
      lg[2] = v[2] - 0.5f * (fs + cs.z);
      lg[3] = v[3] - 0.5f * (fs + cs.w);
      *reinterpret_cast<f32x4*>(&out_logits[rowoff + n0]) = lg;
      f32x4 mg;
      mg[0] = (lb == n0    ) ? lg[0] * (1.0f + ALPHA_) : lg[0];
      mg[1] = (lb == n0 + 1) ? lg[1] * (1.0f + ALPHA_) : lg[1];
      mg[2] = (lb == n0 + 2) ? lg[2] * (1.0f + ALPHA_) : lg[2];
      mg[3] = (lb == n0 + 3) ? lg[3] * (1.0f + ALPHA_) : lg[3];
      *reinterpret_cast<f32x4*>(&out_margin[rowoff + n0]) = mg;
      if (lb >= n0 && lb < n0 + 4) {
        float lv = (lb == n0) ? lg[0] : (lb == n0 + 1) ? lg[1]
                 : (lb == n0 + 2) ? lg[2] : lg[3];
        lik_row[m] = -lv;   // exactly one thread in grid writes each m
      }
    }
  }
  #undef LOADT
  #undef STORET
}

// likelihood = (1/B) * sum_m lik_row[m]; 1024 threads, deterministic tree.
__global__ void lik_reduce_kernel(const float* __restrict__ lik_row,
                                  float* __restrict__ out) {
  int t = threadIdx.x;  // 1024
  float v = 0.f;
  #pragma unroll
  for (int i = 0; i < BATCH / 1024; i++) v += lik_row[t + i * 1024];
  #pragma unroll
  for (int off = 32; off >= 1; off >>= 1) v += __shfl_xor(v, off, 64);
  __shared__ float red[16];
  if ((t & 63) == 0) red[t >> 6] = v;
  __syncthreads();
  if (t == 0) {
    float s = 0.f;
    #pragma unroll
    for (int i = 0; i < 16; i++) s += red[i];
    out[0] = s * (1.0f / BATCH);
  }
}

extern "C" void kernel_launch(void* const* d_in, const int* in_sizes, int n_in,
                              void* d_out, int out_size, void* d_ws, size_t ws_size,
                              hipStream_t stream) {
  const float* feat    = (const float*)d_in[0];
  const int*   label   = (const int*)d_in[1];
  const float* centers = (const float*)d_in[2];

  float* out        = (float*)d_out;
  float* out_logits = out;
  float* out_margin = out + (size_t)BATCH * NCLS;
  float* out_lik    = out + 2 * (size_t)BATCH * NCLS;

  char* ws = (char*)d_ws;
  unsigned short* fbf = (unsigned short*)ws;                                   // 4 MB
  unsigned short* cbf = (unsigned short*)(ws + (size_t)BATCH * FDIM * 2);      // 5 MB
  float* fsq     = (float*)(ws + (size_t)BATCH * FDIM * 2 + (size_t)NCLS * FDIM * 2);
  float* csq     = fsq + BATCH;
  float* lik_row = csq + NCLS;

  prep_kernel<<<(BATCH + NCLS) / 4, 256, 0, stream>>>(feat, centers, fbf, cbf, fsq, csq);
  gemm_kernel<<<NWG, 256, 0, stream>>>(
      fbf, cbf, fsq, csq, label, out_logits, out_margin, lik_row);
  lik_reduce_kernel<<<1, 1024, 0, stream>>>(lik_row, out_lik);
}